// Round 1
// 497.477 us; speedup vs baseline: 1.0045x; 1.0045x over previous
//
#include <hip/hip_runtime.h>

#define NSPL 191                 // 3*64 - 1 spline dims
constexpr float MIN_W = 0.001f, MIN_H = 0.001f, MIN_D = 0.001f;
constexpr float W_A = -10000.0f, AB = 20000.0f;
constexpr float LOG_HALF = -0.69314718055994530942f;
constexpr float LOG_AB   = 9.90348755253612804622f;   // ln(20000)

// 4-float vectors: unaligned (row bases are 4B-aligned only) and 16B (LDS)
typedef float f4  __attribute__((ext_vector_type(4), aligned(4)));
typedef float f4a __attribute__((ext_vector_type(4), aligned(16)));

// DPP add within 16-lane rows; bound_ctrl=1 -> shifted-in lanes contribute 0
template<int CTRL>
__device__ __forceinline__ float dpp_add(float x) {
    int t = __builtin_amdgcn_update_dpp(0, __float_as_int(x), CTRL, 0xf, 0xf, true);
    return x + __int_as_float(t);
}
template<int PAT>
__device__ __forceinline__ float swz_f(float x) {
    return __int_as_float(__builtin_amdgcn_ds_swizzle(__float_as_int(x), PAT));
}
template<int PAT>
__device__ __forceinline__ int swz_i(int x) {
    return __builtin_amdgcn_ds_swizzle(x, PAT);
}

// Per-cut RQS inverse logdet for one 16-lane group. Lane sub owns bins
// 4*sub..4*sub+3. gl = this cut's 192-float LDS slab. Math identical to the
// verified single-cut kernel.
__device__ __forceinline__ float cut_logdet(
    float v, f4 dw, f4 dh, f4 du, f4 ww, f4 wh, f4 wu,
    float* __restrict__ gl, int sub, int cb)
{
    // raw ud (no softplus here) -> LDS
    *(f4a*)(gl + 128 + cb) = (f4a){du.x + wu.x, du.y + wu.y, du.z + wu.z, du.w + wu.w};

    // ---- x ----
    float x = fmaf(v - W_A, 2.0f / AB, -1.0f);
    const bool inside = (x >= -1.0f) && (x <= 1.0f);
    x = fminf(fmaxf(x, -1.0f), 1.0f);

    // ---- exp (no max-subtract; inputs ~0.54 +/- 0.3) ----
    const float ew0 = __expf(dw.x + ww.x), ew1 = __expf(dw.y + ww.y);
    const float ew2 = __expf(dw.z + ww.z), ew3 = __expf(dw.w + ww.w);
    const float eh0 = __expf(dh.x + wh.x), eh1 = __expf(dh.y + wh.y);
    const float eh2 = __expf(dh.z + wh.z), eh3 = __expf(dh.w + wh.w);

    *(f4a*)(gl + 64 + cb) = (f4a){ew0, ew1, ew2, ew3};

    // ---- Sw: 16-lane xor-butterfly ----
    float Sw = (ew0 + ew1) + (ew2 + ew3);
    Sw += swz_f<0x041F>(Sw); Sw += swz_f<0x081F>(Sw);
    Sw += swz_f<0x101F>(Sw); Sw += swz_f<0x201F>(Sw);

    // ---- h: 64-point inclusive cumsum (4 regs x 16 lanes via DPP row scan) ----
    float c0 = eh0, c1 = c0 + eh1, c2 = c1 + eh2, c3 = c2 + eh3;
    float t = c3;
    t = dpp_add<0x111>(t);   // row_shr:1
    t = dpp_add<0x112>(t);   // row_shr:2
    t = dpp_add<0x114>(t);   // row_shr:4
    t = dpp_add<0x118>(t);   // row_shr:8  -> 16-lane inclusive scan of lane totals
    const float base = t - c3;
    c0 += base; c1 += base; c2 += base; c3 += base;

    *(f4a*)(gl + cb) = (f4a){c0, c1, c2, c3};

    const float Sh = swz_f<0x1F0>(c3);     // broadcast lane 15 (group total)

    const float wsc2 = __fdividef(2.0f * (1.0f - 64.0f * MIN_W), Sw);
    const float hsc2 = __fdividef(2.0f * (1.0f - 64.0f * MIN_H), Sh);

    // ---- bin index: count interior right-edges <= x (positions 1..63) ----
    const float off2 = 2.0f * MIN_H;
    const float p1 = (float)(cb + 1);
    const float e0v = fmaf(hsc2, c0, fmaf(off2, p1,        -1.0f));
    const float e1v = fmaf(hsc2, c1, fmaf(off2, p1 + 1.0f, -1.0f));
    const float e2v = fmaf(hsc2, c2, fmaf(off2, p1 + 2.0f, -1.0f));
    float       e3v = fmaf(hsc2, c3, fmaf(off2, p1 + 3.0f, -1.0f));
    if (sub == 15) e3v = 2.0f;             // edge 63 is 1+1e-6: never taken
    int cnt = (x >= e0v) + (x >= e1v) + (x >= e2v) + (x >= e3v);
    cnt += swz_i<0x041F>(cnt); cnt += swz_i<0x081F>(cnt);
    cnt += swz_i<0x101F>(cnt); cnt += swz_i<0x201F>(cnt);
    const int idx = cnt;                   // group-uniform, 0..63

    // ---- epilogue gathers from LDS (same-wave DS ordering, no barrier) ----
    const float capEh_r = gl[(idx > 0) ? (idx - 1) : 0];
    const float capEh   = (idx == 0) ? 0.0f : capEh_r;
    const float C_idx   = gl[idx];
    const float eh_i    = C_idx - capEh;
    const float ew_i    = gl[64 + idx];
    const float u_d0    = gl[128 + idx];               // m = idx   (used when idx>=1)
    const float u_d1    = gl[128 + ((idx + 1) & 63)];  // m = idx+1 (used when idx<=62)
    const float d0 = (idx == 0)  ? 1.0f : (MIN_D + __logf(1.0f + __expf(u_d0)));
    const float d1 = (idx == 63) ? 1.0f : (MIN_D + __logf(1.0f + __expf(u_d1)));

    // ---- RQS inverse logdet ----
    const float in_w = fmaf(wsc2, ew_i, 2.0f * MIN_W);
    const float in_h = fmaf(hsc2, eh_i, 2.0f * MIN_H);
    const float ch_l = fmaf(hsc2, capEh, fmaf(off2, (float)idx, -1.0f));

    const float delta = __fdividef(in_h, in_w);
    const float dy = x - ch_l;
    const float ss = d0 + d1 - 2.0f * delta;
    const float aa = dy * ss + in_h * (delta - d0);
    const float bb = in_h * d0 - dy * ss;
    const float cc = -delta * dy;
    const float disc = bb * bb - 4.0f * aa * cc;
    const float root = __fdividef(2.0f * cc, -bb - sqrtf(fmaxf(disc, 0.0f)));
    const float tom = root * (1.0f - root);
    const float denom = delta + ss * tom;
    const float omr = 1.0f - root;
    const float dnum = delta * delta * (d1 * root * root + 2.0f * delta * tom + d0 * omr * omr);
    const float logabsdet = -(__logf(dnum) - 2.0f * __logf(denom));

    return LOG_HALF + (inside ? logabsdet : 0.0f) - LOG_AB;
}

// 16 lanes per cut (group); TWO cuts per group (ILP x2 for memory-level
// parallelism). All 12 f4 row loads + both scalar gather chains are issued
// up-front so each wave keeps ~2x the outstanding memory requests of the
// single-cut version. Block covers 32 contiguous cuts.
__global__ __launch_bounds__(256, 4) void rqs_g16x2_kernel(
    const float* __restrict__ value,
    const float* __restrict__ dsg,       // delta_spline [n,191]
    const int*   __restrict__ genes_oi,
    const int*   __restrict__ lgi,
    const float* __restrict__ swg,       // spline_weight [5000,191]
    float* __restrict__ out, int n)
{
    // per-group slab: [0..63]=h-cumsum C, [64..127]=ew, [128..191]=raw ud u
    // 32 slabs: groups 0..15 = cut set 0, groups 16..31 = cut set 1
    __shared__ float lds[32 * 192];

    const int sub = threadIdx.x & 15;
    const int gid = threadIdx.x >> 4;                 // 0..15 (group in block)
    const long i0 = (long)blockIdx.x * 32 + gid;      // cut index, set 0
    const long i1 = i0 + 16;                          // cut index, set 1
    const int  ic0 = (int)(i0 < (long)n ? i0 : (long)(n - 1));
    const int  ic1 = (int)(i1 < (long)n ? i1 : (long)(n - 1));

    // scalar gather chains for both cuts, issued together
    const int l0 = lgi[ic0];
    const int l1 = lgi[ic1];
    const float v0 = value[ic0];
    const float v1 = value[ic1];
    const int g0 = genes_oi[l0];
    const int g1 = genes_oi[l1];

    const float* __restrict__ dsr0 = dsg + (long)ic0 * NSPL;
    const float* __restrict__ dsr1 = dsg + (long)ic1 * NSPL;
    const float* __restrict__ swr0 = swg + (long)g0  * NSPL;
    const float* __restrict__ swr1 = swg + (long)g1  * NSPL;

    const int cb = 4 * sub;

    // ---- issue ALL vector loads up-front (12 outstanding f4 per lane) ----
    const f4 dw0 = *(const f4*)(dsr0 + cb);
    const f4 dh0 = *(const f4*)(dsr0 + 64 + cb);
    const f4 du0 = *(const f4*)(dsr0 + 127 + cb);     // padded idx m = cb..cb+3
    const f4 dw1 = *(const f4*)(dsr1 + cb);
    const f4 dh1 = *(const f4*)(dsr1 + 64 + cb);
    const f4 du1 = *(const f4*)(dsr1 + 127 + cb);
    const f4 ww0 = *(const f4*)(swr0 + cb);
    const f4 wh0 = *(const f4*)(swr0 + 64 + cb);
    const f4 wu0 = *(const f4*)(swr0 + 127 + cb);
    const f4 ww1 = *(const f4*)(swr1 + cb);
    const f4 wh1 = *(const f4*)(swr1 + 64 + cb);
    const f4 wu1 = *(const f4*)(swr1 + 127 + cb);

    float* __restrict__ gl0 = lds + gid * 192;
    float* __restrict__ gl1 = lds + (16 + gid) * 192;

    const float r0 = cut_logdet(v0, dw0, dh0, du0, ww0, wh0, wu0, gl0, sub, cb);
    if (sub == 0 && i0 < (long)n) out[i0] = r0;

    const float r1 = cut_logdet(v1, dw1, dh1, du1, ww1, wh1, wu1, gl1, sub, cb);
    if (sub == 0 && i1 < (long)n) out[i1] = r1;
}

extern "C" void kernel_launch(void* const* d_in, const int* in_sizes, int n_in,
                              void* d_out, int out_size, void* d_ws, size_t ws_size,
                              hipStream_t stream) {
    const float* value         = (const float*)d_in[0];
    const float* delta_spline  = (const float*)d_in[1];
    const int*   genes_oi      = (const int*)d_in[2];
    const int*   local_gene_ix = (const int*)d_in[3];
    const float* spline_weight = (const float*)d_in[4];
    float* out = (float*)d_out;

    const int n = in_sizes[0];
    const int cuts_per_block = 32;          // 4 waves x 4 groups x 2 cuts
    const int blocks = (n + cuts_per_block - 1) / cuts_per_block;
    rqs_g16x2_kernel<<<blocks, 256, 0, stream>>>(
        value, delta_spline, genes_oi, local_gene_ix, spline_weight, out, n);
}